// Round 7
// baseline (76.669 us; speedup 1.0000x reference)
//
#include <hip/hip_runtime.h>

typedef __bf16 bf16x4 __attribute__((ext_vector_type(4)));
typedef __bf16 bf16x8 __attribute__((ext_vector_type(8)));
typedef float f32x4 __attribute__((ext_vector_type(4)));

__device__ __forceinline__ f32x4 mfma16(bf16x8 a, bf16x8 b, f32x4 c) {
    return __builtin_amdgcn_mfma_f32_16x16x32_bf16(a, b, c, 0, 0, 0);
}

// Fused 3-layer MLP: out = relu(relu(x@W0^T+b0)@W1^T+b1)@W2^T + b2
// x:[N,64] f32 -> out:[N,32] f32. bf16 MFMA, fp32 accum.
// Swapped-operand MFMA (D = W·X^T): lane (lr,lg) holds H[ch=16t+4lg+r][node=lr].
// R4 structure (best: 69.5us): fw0/fw2 hoisted (48 VGPR), fw1 streamed from LDS,
// 1-deep x prefetch, nontemporal stores, no launch-bounds forcing.
// R7 change: half the work per block (128 nodes = 4 waves x 2 tiles, grid 7813)
// to shrink the ragged-dispatch tail from ~4.6% to ~2%.
__global__ __launch_bounds__(256) void cheb_mlp_kernel(
    const float* __restrict__ x,
    const float* __restrict__ W0, const float* __restrict__ b0v,
    const float* __restrict__ W1, const float* __restrict__ b1v,
    const float* __restrict__ W2, const float* __restrict__ b2v,
    float* __restrict__ out, int n_nodes)
{
    __shared__ __bf16 w0s[64][72];
    __shared__ __bf16 w1s[64][72];
    __shared__ __bf16 w2s[32][72];
    __shared__ float bias0[64], bias1[64], bias2[32];
    __shared__ __bf16 hbuf[4][16][72];   // per-wave activation staging

    const int tid = threadIdx.x;

    for (int i = tid; i < 64 * 64; i += 256) {
        int r = i >> 6, c = i & 63;
        w0s[r][c] = (__bf16)W0[i];
        w1s[r][c] = (__bf16)W1[i];
    }
    for (int i = tid; i < 32 * 64; i += 256) {
        w2s[i >> 6][i & 63] = (__bf16)W2[i];
    }
    if (tid < 64)      { bias0[tid] = b0v[tid]; bias1[tid] = b1v[tid]; }
    else if (tid < 96) { bias2[tid - 64] = b2v[tid - 64]; }
    __syncthreads();

    const int wave = tid >> 6;
    const int lane = tid & 63;
    const int lr = lane & 15;   // A-row (W channel) / D-col (node)
    const int lg = lane >> 4;   // k-offset 8*lg; D-row 4*lg + r

    // Hoist fw0 + fw2 only (A-operand layout: W[16t+lr][32s+8lg+j]) = 48 VGPR.
    bf16x8 fw0[4][2], fw2[2][2];
#pragma unroll
    for (int t = 0; t < 4; ++t)
#pragma unroll
        for (int s = 0; s < 2; ++s)
            fw0[t][s] = *(const bf16x8*)&w0s[t * 16 + lr][s * 32 + lg * 8];
#pragma unroll
    for (int t = 0; t < 2; ++t)
#pragma unroll
        for (int s = 0; s < 2; ++s)
            fw2[t][s] = *(const bf16x8*)&w2s[t * 16 + lr][s * 32 + lg * 8];

    const int wave_base = blockIdx.x * 128 + wave * 32;   // 2 tiles of 16 per wave
    if (wave_base >= n_nodes) return;            // no barriers after this point
    const int rem = (n_nodes - wave_base) >> 4;  // N%16==0: whole tiles only
    const int nt = rem < 2 ? rem : 2;

    const float* xbase = x + (size_t)(wave_base + lr) * 64 + lg * 8;

    f32x4 cx0, cx1, cx2, cx3;
    {
        const float* xp = xbase;
        cx0 = *(const f32x4*)(xp);
        cx1 = *(const f32x4*)(xp + 4);
        cx2 = *(const f32x4*)(xp + 32);
        cx3 = *(const f32x4*)(xp + 36);
    }

#pragma unroll
    for (int mt = 0; mt < 2; ++mt) {
        if (mt >= nt) break;
        const int m_cur = wave_base + mt * 16;

        // 1-deep prefetch of next tile.
        f32x4 nx0, nx1, nx2, nx3;
        const bool has_next = (mt + 1 < nt);
        if (has_next) {
            const float* xp = xbase + (size_t)(mt + 1) * 1024;
            nx0 = *(const f32x4*)(xp);
            nx1 = *(const f32x4*)(xp + 4);
            nx2 = *(const f32x4*)(xp + 32);
            nx3 = *(const f32x4*)(xp + 36);
        }

        // X fragment (B-operand layout: X[node=lr][32s+8lg+j]), fp32->bf16.
        bf16x8 ax0, ax1;
#pragma unroll
        for (int j = 0; j < 4; ++j) {
            ax0[j]     = (__bf16)cx0[j];
            ax0[j + 4] = (__bf16)cx1[j];
            ax1[j]     = (__bf16)cx2[j];
            ax1[j + 4] = (__bf16)cx3[j];
        }

        // ---- layer 0 (fw0 from registers) ----
        f32x4 acc[4];
#pragma unroll
        for (int t = 0; t < 4; ++t) {
            acc[t] = *(const f32x4*)&bias0[t * 16 + lg * 4];
            acc[t] = mfma16(fw0[t][0], ax0, acc[t]);
            acc[t] = mfma16(fw0[t][1], ax1, acc[t]);
        }
#pragma unroll
        for (int t = 0; t < 4; ++t) {
            bf16x4 pk;
#pragma unroll
            for (int r = 0; r < 4; ++r) {
                float v = acc[t][r];
                pk[r] = (__bf16)(v > 0.f ? v : 0.f);
            }
            *(bf16x4*)&hbuf[wave][lr][t * 16 + lg * 4] = pk;
        }

        // ---- layer 1 (fw1 streamed from LDS, <=2-way bank aliasing = free) ----
        bf16x8 ah0 = *(const bf16x8*)&hbuf[wave][lr][lg * 8];
        bf16x8 ah1 = *(const bf16x8*)&hbuf[wave][lr][32 + lg * 8];
#pragma unroll
        for (int t = 0; t < 4; ++t) {
            bf16x8 f0 = *(const bf16x8*)&w1s[t * 16 + lr][lg * 8];
            bf16x8 f1 = *(const bf16x8*)&w1s[t * 16 + lr][32 + lg * 8];
            acc[t] = *(const f32x4*)&bias1[t * 16 + lg * 4];
            acc[t] = mfma16(f0, ah0, acc[t]);
            acc[t] = mfma16(f1, ah1, acc[t]);
        }
#pragma unroll
        for (int t = 0; t < 4; ++t) {
            bf16x4 pk;
#pragma unroll
            for (int r = 0; r < 4; ++r) {
                float v = acc[t][r];
                pk[r] = (__bf16)(v > 0.f ? v : 0.f);
            }
            *(bf16x4*)&hbuf[wave][lr][t * 16 + lg * 4] = pk;
        }

        // ---- layer 2 (fw2 from registers, no relu): nontemporal dwordx4 stores ----
        bf16x8 ag0 = *(const bf16x8*)&hbuf[wave][lr][lg * 8];
        bf16x8 ag1 = *(const bf16x8*)&hbuf[wave][lr][32 + lg * 8];
#pragma unroll
        for (int t = 0; t < 2; ++t) {
            f32x4 a2 = *(const f32x4*)&bias2[t * 16 + lg * 4];
            a2 = mfma16(fw2[t][0], ag0, a2);
            a2 = mfma16(fw2[t][1], ag1, a2);
            __builtin_nontemporal_store(a2, (f32x4*)&out[(size_t)(m_cur + lr) * 32 + t * 16 + lg * 4]);
        }

        if (has_next) { cx0 = nx0; cx1 = nx1; cx2 = nx2; cx3 = nx3; }
    }
}

extern "C" void kernel_launch(void* const* d_in, const int* in_sizes, int n_in,
                              void* d_out, int out_size, void* d_ws, size_t ws_size,
                              hipStream_t stream) {
    const float* x  = (const float*)d_in[0];
    // d_in[1] = edge_index (int64), d_in[2] = edge_weight — dead inputs (ChebConv K=1).
    const float* W0 = (const float*)d_in[3];
    const float* b0 = (const float*)d_in[4];
    const float* W1 = (const float*)d_in[5];
    const float* b1 = (const float*)d_in[6];
    const float* W2 = (const float*)d_in[7];
    const float* b2 = (const float*)d_in[8];
    float* out = (float*)d_out;

    const int n_nodes = in_sizes[0] / 64;           // 1,000,000
    const int grid = (n_nodes + 127) / 128;         // 128 nodes / block
    cheb_mlp_kernel<<<grid, 256, 0, stream>>>(x, W0, b0, W1, b1, W2, b2, out, n_nodes);
}

// Round 8
// 64.129 us; speedup vs baseline: 1.1955x; 1.1955x over previous
//
#include <hip/hip_runtime.h>

typedef __bf16 bf16x4 __attribute__((ext_vector_type(4)));
typedef __bf16 bf16x8 __attribute__((ext_vector_type(8)));
typedef float f32x4 __attribute__((ext_vector_type(4)));

__device__ __forceinline__ f32x4 mfma16(bf16x8 a, bf16x8 b, f32x4 c) {
    return __builtin_amdgcn_mfma_f32_16x16x32_bf16(a, b, c, 0, 0, 0);
}

// Fused 3-layer MLP: out = relu(relu(x@W0^T+b0)@W1^T+b1)@W2^T + b2
// x:[N,64] f32 -> out:[N,32] f32. bf16 MFMA, fp32 accum.
// Swapped-operand MFMA (D = W·X^T): lane (lr,lg) holds H[ch=16t+4lg+r][node=lr].
// R8: persistent grid. 1024 blocks (4 resident/CU at 33KB LDS) x 4 waves; each
// wave round-robins over 16-node tiles (tile = g, g+4096, ...). Prologue
// (weight stage+hoist) runs 1024x instead of 3907x (R7 measured ~1.8us/1000
// blocks of prologue wall cost). Inner loop = R4 exactly: fw0/fw2 in registers,
// fw1 streamed from LDS, 1-deep x prefetch, nontemporal dwordx4 stores.
__global__ __launch_bounds__(256) void cheb_mlp_kernel(
    const float* __restrict__ x,
    const float* __restrict__ W0, const float* __restrict__ b0v,
    const float* __restrict__ W1, const float* __restrict__ b1v,
    const float* __restrict__ W2, const float* __restrict__ b2v,
    float* __restrict__ out, int n_nodes)
{
    __shared__ __bf16 w0s[64][72];
    __shared__ __bf16 w1s[64][72];
    __shared__ __bf16 w2s[32][72];
    __shared__ float bias0[64], bias1[64], bias2[32];
    __shared__ __bf16 hbuf[4][16][72];   // per-wave activation staging

    const int tid = threadIdx.x;

    for (int i = tid; i < 64 * 64; i += 256) {
        int r = i >> 6, c = i & 63;
        w0s[r][c] = (__bf16)W0[i];
        w1s[r][c] = (__bf16)W1[i];
    }
    for (int i = tid; i < 32 * 64; i += 256) {
        w2s[i >> 6][i & 63] = (__bf16)W2[i];
    }
    if (tid < 64)      { bias0[tid] = b0v[tid]; bias1[tid] = b1v[tid]; }
    else if (tid < 96) { bias2[tid - 64] = b2v[tid - 64]; }
    __syncthreads();

    const int wave = tid >> 6;
    const int lane = tid & 63;
    const int lr = lane & 15;   // A-row (W channel) / D-col (node)
    const int lg = lane >> 4;   // k-offset 8*lg; D-row 4*lg + r

    // Hoist fw0 + fw2 only (A-operand layout: W[16t+lr][32s+8lg+j]) = 48 VGPR.
    bf16x8 fw0[4][2], fw2[2][2];
#pragma unroll
    for (int t = 0; t < 4; ++t)
#pragma unroll
        for (int s = 0; s < 2; ++s)
            fw0[t][s] = *(const bf16x8*)&w0s[t * 16 + lr][s * 32 + lg * 8];
#pragma unroll
    for (int t = 0; t < 2; ++t)
#pragma unroll
        for (int s = 0; s < 2; ++s)
            fw2[t][s] = *(const bf16x8*)&w2s[t * 16 + lr][s * 32 + lg * 8];

    // Persistent round-robin tile assignment.
    const int total_tiles = n_nodes >> 4;             // N%16==0
    const int g = blockIdx.x * 4 + wave;              // global wave id
    const int wstride = gridDim.x * 4;                // 4096
    if (g >= total_tiles) return;
    const int niter = (total_tiles - g + wstride - 1) / wstride;

    // Per-lane base pointers; advance by wstride tiles each iteration.
    const size_t tile_step = (size_t)wstride * 16 * 64;   // floats per iteration
    const float* xp = x + (size_t)g * 16 * 64 + (size_t)lr * 64 + lg * 8;

    f32x4 cx0 = *(const f32x4*)(xp);
    f32x4 cx1 = *(const f32x4*)(xp + 4);
    f32x4 cx2 = *(const f32x4*)(xp + 32);
    f32x4 cx3 = *(const f32x4*)(xp + 36);

    int m_cur = g * 16;
    const int m_step = wstride * 16;

    for (int it = 0; it < niter; ++it) {
        // 1-deep prefetch of next assigned tile.
        f32x4 nx0, nx1, nx2, nx3;
        const bool has_next = (it + 1 < niter);
        if (has_next) {
            const float* np = xp + tile_step;
            nx0 = *(const f32x4*)(np);
            nx1 = *(const f32x4*)(np + 4);
            nx2 = *(const f32x4*)(np + 32);
            nx3 = *(const f32x4*)(np + 36);
        }

        // X fragment (B-operand layout: X[node=lr][32s+8lg+j]), fp32->bf16.
        bf16x8 ax0, ax1;
#pragma unroll
        for (int j = 0; j < 4; ++j) {
            ax0[j]     = (__bf16)cx0[j];
            ax0[j + 4] = (__bf16)cx1[j];
            ax1[j]     = (__bf16)cx2[j];
            ax1[j + 4] = (__bf16)cx3[j];
        }

        // ---- layer 0 (fw0 from registers) ----
        f32x4 acc[4];
#pragma unroll
        for (int t = 0; t < 4; ++t) {
            acc[t] = *(const f32x4*)&bias0[t * 16 + lg * 4];
            acc[t] = mfma16(fw0[t][0], ax0, acc[t]);
            acc[t] = mfma16(fw0[t][1], ax1, acc[t]);
        }
#pragma unroll
        for (int t = 0; t < 4; ++t) {
            bf16x4 pk;
#pragma unroll
            for (int r = 0; r < 4; ++r) {
                float v = acc[t][r];
                pk[r] = (__bf16)(v > 0.f ? v : 0.f);
            }
            *(bf16x4*)&hbuf[wave][lr][t * 16 + lg * 4] = pk;
        }

        // ---- layer 1 (fw1 streamed from LDS, <=2-way bank aliasing = free) ----
        bf16x8 ah0 = *(const bf16x8*)&hbuf[wave][lr][lg * 8];
        bf16x8 ah1 = *(const bf16x8*)&hbuf[wave][lr][32 + lg * 8];
#pragma unroll
        for (int t = 0; t < 4; ++t) {
            bf16x8 f0 = *(const bf16x8*)&w1s[t * 16 + lr][lg * 8];
            bf16x8 f1 = *(const bf16x8*)&w1s[t * 16 + lr][32 + lg * 8];
            acc[t] = *(const f32x4*)&bias1[t * 16 + lg * 4];
            acc[t] = mfma16(f0, ah0, acc[t]);
            acc[t] = mfma16(f1, ah1, acc[t]);
        }
#pragma unroll
        for (int t = 0; t < 4; ++t) {
            bf16x4 pk;
#pragma unroll
            for (int r = 0; r < 4; ++r) {
                float v = acc[t][r];
                pk[r] = (__bf16)(v > 0.f ? v : 0.f);
            }
            *(bf16x4*)&hbuf[wave][lr][t * 16 + lg * 4] = pk;
        }

        // ---- layer 2 (fw2 from registers, no relu): nontemporal dwordx4 stores ----
        bf16x8 ag0 = *(const bf16x8*)&hbuf[wave][lr][lg * 8];
        bf16x8 ag1 = *(const bf16x8*)&hbuf[wave][lr][32 + lg * 8];
#pragma unroll
        for (int t = 0; t < 2; ++t) {
            f32x4 a2 = *(const f32x4*)&bias2[t * 16 + lg * 4];
            a2 = mfma16(fw2[t][0], ag0, a2);
            a2 = mfma16(fw2[t][1], ag1, a2);
            __builtin_nontemporal_store(a2, (f32x4*)&out[(size_t)(m_cur + lr) * 32 + t * 16 + lg * 4]);
        }

        if (has_next) { cx0 = nx0; cx1 = nx1; cx2 = nx2; cx3 = nx3; }
        xp += tile_step;
        m_cur += m_step;
    }
}

extern "C" void kernel_launch(void* const* d_in, const int* in_sizes, int n_in,
                              void* d_out, int out_size, void* d_ws, size_t ws_size,
                              hipStream_t stream) {
    const float* x  = (const float*)d_in[0];
    // d_in[1] = edge_index (int64), d_in[2] = edge_weight — dead inputs (ChebConv K=1).
    const float* W0 = (const float*)d_in[3];
    const float* b0 = (const float*)d_in[4];
    const float* W1 = (const float*)d_in[5];
    const float* b1 = (const float*)d_in[6];
    const float* W2 = (const float*)d_in[7];
    const float* b2 = (const float*)d_in[8];
    float* out = (float*)d_out;

    const int n_nodes = in_sizes[0] / 64;   // 1,000,000
    const int grid = 1024;                  // persistent: 4 blocks/CU x 256 CUs
    cheb_mlp_kernel<<<grid, 256, 0, stream>>>(x, W0, b0, W1, b1, W2, b2, out, n_nodes);
}